// Round 9
// baseline (1292.407 us; speedup 1.0000x reference)
//
#include <hip/hip_runtime.h>
#include <stdint.h>

// GRU decoder: 65536 rows, H=256, T=12, D_OUT=64.
// R9 redesign: swapped-operand MFMA (D^T = W x h^T) so the recurrent state
// h/rh/h_new lives ENTIRELY in registers as B-fragments (lane=row).
// No LDS state tile, no elementwise LDS traffic. LDS = weight-panel ring
// (3 x 32KB, global_load_lds, vmcnt(8)) + 3.3KB expanded biases.
// 512 blocks x 256 thr (4 waves, 32 rows each); LDS 100KB forces 1 block/CU
// -> 1 wave/SIMD -> 512-VGPR budget -> live set ~300 regs, zero spill.
// C-layout (lane=row, e-pattern=outcol) -> B-frag repack via cvt + shfl_xor(32).

#define TSTEPS 12
#define AS3 __attribute__((address_space(3)))

typedef _Float16 f16x8 __attribute__((ext_vector_type(8)));
typedef _Float16 f16x2 __attribute__((ext_vector_type(2)));
typedef float    f32x16 __attribute__((ext_vector_type(16)));
typedef float    f32x4  __attribute__((ext_vector_type(4)));
typedef uint32_t u32x4  __attribute__((ext_vector_type(4)));

typedef AS3 uint8_t       u8l;
typedef const AS3 uint8_t cu8l;

// ws: f16 weights (panels of 64 rows x 256 k = 32KB):
//   0-3 gate-r(folded), 4-7 gate-z(folded), 8-11 W1, 12-15 W2, 16 Wp
// then f32 bias block, expanded to C-layout e-pattern order:
//   [type r/z/o][chunk c][tile n][kg][e]  (3*256 f32) + pb [n][kg][e] (64 f32)
#define WG_E (512*256)
#define W1_E (256*256)
#define WS_W_F16 (WG_E + 2*W1_E + 64*256)      // 278528 f16
#define BIAS_F32 832
#define WS_BYTES (WS_W_F16*2 + BIAS_F32*4)     // 560384

__global__ void prep_weights(const float* __restrict__ gw,
                             const float* __restrict__ ow,
                             const float* __restrict__ pw,
                             const float* __restrict__ gb,
                             const float* __restrict__ ob,
                             const float* __restrict__ pb,
                             _Float16* __restrict__ ws)
{
    int idx = blockIdx.x*256 + threadIdx.x;
    if (idx < WG_E) {                           // folded gates
        int j = idx >> 8, k = idx & 255;
        ws[idx] = (_Float16)(gw[j*512 + k] + gw[j*512 + 256 + k]);
    } else if (idx < WG_E + W1_E) {             // W1 = out_w[:, :256]
        int i = idx - WG_E; int r = i >> 8, c = i & 255;
        ws[idx] = (_Float16)ow[r*512 + c];
    } else if (idx < WG_E + 2*W1_E) {           // W2 = out_w[:, 256:]
        int i = idx - WG_E - W1_E; int r = i >> 8, c = i & 255;
        ws[idx] = (_Float16)ow[r*512 + 256 + c];
    } else if (idx < WS_W_F16) {                // Wp
        ws[idx] = (_Float16)pw[idx - WG_E - 2*W1_E];
    } else if (idx < WS_W_F16 + BIAS_F32) {     // expanded biases (f32)
        int b = idx - WS_W_F16;
        float* bd = (float*)(ws + WS_W_F16);
        if (b < 768) {
            int type = b >> 8, r = b & 255;
            int c = r >> 6, n = (r >> 5) & 1, kg = (r >> 4) & 1, e = r & 15;
            int col = 64*c + 32*n + 4*kg + (e & 3) + 8*(e >> 2);
            bd[b] = (type == 0) ? gb[col] : (type == 1) ? gb[256 + col] : ob[col];
        } else {
            int i = b - 768;
            int n = (i >> 5) & 1, kg = (i >> 4) & 1, e = i & 15;
            bd[b] = pb[32*n + 4*kg + (e & 3) + 8*(e >> 2)];
        }
    }
}

__device__ __forceinline__ float sigm(float x)  { return 1.0f/(1.0f+__expf(-x)); }
__device__ __forceinline__ float tanh_(float x) { return 1.0f - 2.0f/(1.0f+__expf(2.0f*x)); }

// stage one 32KB panel (4 waves x 8 gll16). LDS dest linear; global source
// pre-applies the inverse chunk-XOR layout permutation.
__device__ __forceinline__ void stage(const uint8_t* __restrict__ Wp,
                                      u8l* slot, int w, int lane)
{
    #pragma unroll
    for (int i = 0; i < 8; ++i) {
        int d  = w*8192 + i*1024;
        int dl = d + lane*16;
        int chunk = (dl>>7)&31, sl = (dl>>4)&7;
        int row = ((dl>>12)<<3) | (sl ^ (chunk&7));
        int s   = row*512 + chunk*16;
        __builtin_amdgcn_global_load_lds(
            (const __attribute__((address_space(1))) uint32_t*)(Wp + s),
            (AS3 uint32_t*)(slot + d), 16, 0, 0);
    }
}

// load f32x16 bias (broadcast within kg-half)
__device__ __forceinline__ f32x16 ldbias(cu8l* p) {
    f32x16 r;
    #pragma unroll
    for (int j = 0; j < 4; ++j) {
        f32x4 t = *(const AS3 f32x4*)(p + j*16);
        r[j*4+0]=t[0]; r[j*4+1]=t[1]; r[j*4+2]=t[2]; r[j*4+3]=t[3];
    }
    return r;
}

// C-layout 16-col block (8 f32 per lane, e-pattern) -> B-frag f16x8.
// Target lane kg', f16 j: k%16 = 8kg'+j; source = (kg_src=j>>2, el=4kg'+(j&3)).
// kg'=0: [self el0..3 | partner el0..3]; kg'=1: [partner el4..7 | self el4..7].
__device__ __forceinline__ f16x8 pkblk(const float* s, int kg) {
    f16x2 a01 = {(_Float16)s[0], (_Float16)s[1]};
    f16x2 a23 = {(_Float16)s[2], (_Float16)s[3]};
    f16x2 a45 = {(_Float16)s[4], (_Float16)s[5]};
    f16x2 a67 = {(_Float16)s[6], (_Float16)s[7]};
    uint32_t w01 = __builtin_bit_cast(uint32_t, a01);
    uint32_t w23 = __builtin_bit_cast(uint32_t, a23);
    uint32_t w45 = __builtin_bit_cast(uint32_t, a45);
    uint32_t w67 = __builtin_bit_cast(uint32_t, a67);
    uint32_t s01 = __shfl_xor(w01, 32, 64);
    uint32_t s23 = __shfl_xor(w23, 32, 64);
    uint32_t s45 = __shfl_xor(w45, 32, 64);
    uint32_t s67 = __shfl_xor(w67, 32, 64);
    u32x4 u = { kg ? s45 : w01, kg ? s67 : w23,
                kg ? w45 : s01, kg ? w67 : s23 };
    return __builtin_bit_cast(f16x8, u);
}

// one panel GEMM: acc_n += W[32n+(l&31), k] * B (B = reg-resident h or rh)
__device__ __forceinline__ void gemm2(cu8l* pan, int R0, int R1,
                                      const f16x8* B, f32x16& a0, f32x16& a1) {
    #pragma unroll
    for (int ks = 0; ks < 16; ++ks) {
        const int xk = ((2*ks)&7) << 4;
        f16x8 w0 = *(const AS3 f16x8*)(pan + ((R0 ^ xk) + ks*256));
        f16x8 w1 = *(const AS3 f16x8*)(pan + ((R1 ^ xk) + ks*256));
        a0 = __builtin_amdgcn_mfma_f32_32x32x16_f16(w0, B[ks], a0, 0, 0, 0);
        a1 = __builtin_amdgcn_mfma_f32_32x32x16_f16(w1, B[ks], a1, 0, 0, 0);
    }
}

// phase: wait panel (vmcnt(8): 2 stages of 8 in flight) -> barrier ->
// stage 2-ahead -> compute. One barrier per phase; no cross-wave state deps.
#define PHASE(SP, ...) do {                                                 \
    asm volatile("s_waitcnt vmcnt(8)" ::: "memory");                        \
    asm volatile("s_waitcnt lgkmcnt(0)" ::: "memory");                      \
    __builtin_amdgcn_s_barrier();                                           \
    asm volatile("" ::: "memory");                                          \
    stage(W + (SP)*32768, WbL + sS*32768, w, lane);                         \
    { cu8l* pan = WbL + sC*32768; __VA_ARGS__; }                            \
    sC = (sC == 2) ? 0 : sC + 1;                                            \
    sS = (sS == 2) ? 0 : sS + 1;                                            \
} while (0)

__global__ __launch_bounds__(256, 1)
void gru_dec(const float* __restrict__ h_in, const _Float16* __restrict__ Wf,
             float* __restrict__ out)
{
    __shared__ __align__(16) uint8_t lds_[102400];
    u8l* ldsb = (u8l*)lds_;
    u8l* WbL  = ldsb;                     // 3 x 32KB panel ring
    u8l* biasL = ldsb + 98304;            // 3.3KB expanded biases
    const uint8_t* W = (const uint8_t*)Wf;

    const int tid  = threadIdx.x;
    const int lane = tid & 63;
    const int w    = tid >> 6;            // wave 0..3, owns 32 rows
    const int bl31 = lane & 31;
    const int kg   = lane >> 5;
    const int l7   = lane & 7;
    const size_t rowg = (size_t)blockIdx.x*128 + w*32 + bl31;

    // ---- h -> registers as B-frags: h[ks] = h[rowg, 16ks+8kg+0..7] ----
    f16x8 h[16], rh[16], hn[16];
    {
        const float* hs = h_in + rowg*256 + kg*8;
        #pragma unroll
        for (int ks = 0; ks < 16; ++ks) {
            f32x4 x = *(const f32x4*)(hs + ks*16);
            f32x4 y = *(const f32x4*)(hs + ks*16 + 4);
            f16x8 v = {(_Float16)x[0],(_Float16)x[1],(_Float16)x[2],(_Float16)x[3],
                       (_Float16)y[0],(_Float16)y[1],(_Float16)y[2],(_Float16)y[3]};
            h[ks] = v;
        }
    }
    // ---- biases ws -> LDS ----
    {
        const float* bsrc = (const float*)(Wf + WS_W_F16);
        for (int i = tid; i < BIAS_F32; i += 256)
            *(AS3 float*)(biasL + i*4) = bsrc[i];
    }
    __syncthreads();                      // drains h loads + bias writes

    // per-lane panel-read bases (chunk-XOR layout)
    const int R0 = ((bl31 >> 3))*4096 + kg*128 + ((l7 ^ kg) << 4);
    const int R1 = R0 + 4*4096;
    cu8l* bK = biasL + kg*64;             // + type/chunk/tile offsets below

    stage(W + 0*32768, WbL,         w, lane);   // panel r0
    stage(W + 1*32768, WbL + 32768, w, lane);   // panel r1
    int sC = 0, sS = 2;

    for (int t = 0; t < TSTEPS; ++t) {
        f32x16 o0, o1;
        f16x8 zb[4];

        // ---- r gates (panels 0..3): rh[4c+i] = sigm(h@Wr_c + rb) * h ----
#define RPH(SP_STG, C)                                                        \
        PHASE(SP_STG, {                                                       \
            f32x16 a0 = ldbias(bK + (C)*256);                                 \
            f32x16 a1 = ldbias(bK + (C)*256 + 128);                           \
            gemm2(pan, R0, R1, h, a0, a1);                                    \
            float s[16]; f16x8 sb0, sb1, sb2, sb3;                            \
            _Pragma("unroll") for (int e = 0; e < 16; ++e) s[e] = sigm(a0[e]);\
            sb0 = pkblk(s, kg); sb1 = pkblk(s + 8, kg);                       \
            _Pragma("unroll") for (int e = 0; e < 16; ++e) s[e] = sigm(a1[e]);\
            sb2 = pkblk(s, kg); sb3 = pkblk(s + 8, kg);                       \
            rh[4*(C)+0] = sb0*h[4*(C)+0]; rh[4*(C)+1] = sb1*h[4*(C)+1];       \
            rh[4*(C)+2] = sb2*h[4*(C)+2]; rh[4*(C)+3] = sb3*h[4*(C)+3]; })
        RPH(2, 0); RPH(3, 1); RPH(4, 2); RPH(8, 3);
#undef RPH

        // ---- per chunk c: z -> W1 -> W2+combine ----
#define ZPH(SP_STG, C)                                                        \
        PHASE(SP_STG, {                                                       \
            f32x16 a0 = ldbias(bK + 1024 + (C)*256);                          \
            f32x16 a1 = ldbias(bK + 1024 + (C)*256 + 128);                    \
            gemm2(pan, R0, R1, h, a0, a1);                                    \
            float s[16];                                                      \
            _Pragma("unroll") for (int e = 0; e < 16; ++e) s[e] = sigm(a0[e]);\
            zb[0] = pkblk(s, kg); zb[1] = pkblk(s + 8, kg);                   \
            _Pragma("unroll") for (int e = 0; e < 16; ++e) s[e] = sigm(a1[e]);\
            zb[2] = pkblk(s, kg); zb[3] = pkblk(s + 8, kg); })
#define W1PH(SP_STG, C)                                                       \
        PHASE(SP_STG, {                                                       \
            o0 = ldbias(bK + 2048 + (C)*256);                                 \
            o1 = ldbias(bK + 2048 + (C)*256 + 128);                           \
            gemm2(pan, R0, R1, h, o0, o1); })
#define W2PH(SP_STG, C)                                                       \
        PHASE(SP_STG, {                                                       \
            gemm2(pan, R0, R1, rh, o0, o1);                                   \
            float s[16]; f16x8 ub[4];                                         \
            _Pragma("unroll") for (int e = 0; e < 16; ++e) s[e] = tanh_(o0[e]);\
            ub[0] = pkblk(s, kg); ub[1] = pkblk(s + 8, kg);                   \
            _Pragma("unroll") for (int e = 0; e < 16; ++e) s[e] = tanh_(o1[e]);\
            ub[2] = pkblk(s, kg); ub[3] = pkblk(s + 8, kg);                   \
            _Pragma("unroll") for (int i = 0; i < 4; ++i)                     \
                hn[4*(C)+i] = ub[i] + zb[i]*(h[4*(C)+i] - ub[i]); })

        ZPH(12, 0); W1PH(5, 0); W2PH(9,  0);
        ZPH(13, 1); W1PH(6, 1); W2PH(10, 1);
        ZPH(14, 2); W1PH(7, 2); W2PH(11, 2);
        ZPH(15, 3); W1PH(16,3); W2PH(0,  3);
#undef ZPH
#undef W1PH
#undef W2PH

        // h <- h_new
        #pragma unroll
        for (int i = 0; i < 16; ++i) h[i] = hn[i];

        // ---- proj (panel 16): out_t = h_new @ Wp^T + pb ----
        PHASE(1, {
            f32x16 a0 = ldbias(bK + 3072);
            f32x16 a1 = ldbias(bK + 3072 + 128);
            gemm2(pan, R0, R1, h, a0, a1);
            float* op = out + (rowg*TSTEPS + t)*64;
            _Pragma("unroll")
            for (int e = 0; e < 16; ++e) {
                int c0 = (e & 3) + 8*(e >> 2) + 4*kg;
                op[c0]      = a0[e];
                op[32 + c0] = a1[e];
            }
        });
    }
}

extern "C" void kernel_launch(void* const* d_in, const int* in_sizes, int n_in,
                              void* d_out, int out_size, void* d_ws, size_t ws_size,
                              hipStream_t stream) {
    // inputs: 0:x(=12) 1:h 2:gate_w 3:gate_b 4:out_w 5:out_b 6:proj_w 7:proj_b
    const float* h  = (const float*)d_in[1];
    const float* gw = (const float*)d_in[2];
    const float* gb = (const float*)d_in[3];
    const float* ow = (const float*)d_in[4];
    const float* ob = (const float*)d_in[5];
    const float* pw = (const float*)d_in[6];
    const float* pb = (const float*)d_in[7];
    if (ws_size < (size_t)WS_BYTES) return;
    _Float16* ws = (_Float16*)d_ws;

    hipLaunchKernelGGL(prep_weights, dim3((WS_W_F16 + BIAS_F32 + 255)/256), dim3(256),
                       0, stream, gw, ow, pw, gb, ob, pb, ws);
    hipLaunchKernelGGL(gru_dec, dim3(65536/128), dim3(256), 0, stream,
                       h, ws, (float*)d_out);
}

// Round 10
// 727.617 us; speedup vs baseline: 1.7762x; 1.7762x over previous
//
#include <hip/hip_runtime.h>
#include <stdint.h>

// GRU decoder: 65536 rows, H=256, T=12, D_OUT=64.
// R10: R9 swapped-operand register-state design, but 8 waves/block
// (2 waves/SIMD for TLP) x 32 rows/wave = 256 rows/block, 256 blocks = 1/CU.
// State h/rh/hn lives in registers as B-frags (lane=row). LDS = 3x32KB
// weight-panel ring (global_load_lds, vmcnt(4)) + 3.3KB biases.
// Register budget 256/wave: state 192 + zb 16 + temps ~26 = ~234 VGPR,
// o0/o1 accumulators in AGPRs.

#define TSTEPS 12
#define AS3 __attribute__((address_space(3)))

typedef _Float16 f16x8 __attribute__((ext_vector_type(8)));
typedef _Float16 f16x2 __attribute__((ext_vector_type(2)));
typedef float    f32x16 __attribute__((ext_vector_type(16)));
typedef float    f32x4  __attribute__((ext_vector_type(4)));
typedef uint32_t u32x4  __attribute__((ext_vector_type(4)));

typedef AS3 uint8_t       u8l;
typedef const AS3 uint8_t cu8l;

// ws: f16 weights (panels of 64 rows x 256 k = 32KB):
//   0-3 gate-r(folded), 4-7 gate-z(folded), 8-11 W1, 12-15 W2, 16 Wp
// then f32 bias block in C-layout e-pattern order:
//   [type r/z/o][chunk][tile n][kg][e] (768 f32) + pb [n][kg][e] (64 f32)
#define WG_E (512*256)
#define W1_E (256*256)
#define WS_W_F16 (WG_E + 2*W1_E + 64*256)
#define BIAS_F32 832
#define WS_BYTES (WS_W_F16*2 + BIAS_F32*4)

__global__ void prep_weights(const float* __restrict__ gw,
                             const float* __restrict__ ow,
                             const float* __restrict__ pw,
                             const float* __restrict__ gb,
                             const float* __restrict__ ob,
                             const float* __restrict__ pb,
                             _Float16* __restrict__ ws)
{
    int idx = blockIdx.x*256 + threadIdx.x;
    if (idx < WG_E) {                           // folded gates
        int j = idx >> 8, k = idx & 255;
        ws[idx] = (_Float16)(gw[j*512 + k] + gw[j*512 + 256 + k]);
    } else if (idx < WG_E + W1_E) {             // W1 = out_w[:, :256]
        int i = idx - WG_E; int r = i >> 8, c = i & 255;
        ws[idx] = (_Float16)ow[r*512 + c];
    } else if (idx < WG_E + 2*W1_E) {           // W2 = out_w[:, 256:]
        int i = idx - WG_E - W1_E; int r = i >> 8, c = i & 255;
        ws[idx] = (_Float16)ow[r*512 + 256 + c];
    } else if (idx < WS_W_F16) {                // Wp
        ws[idx] = (_Float16)pw[idx - WG_E - 2*W1_E];
    } else if (idx < WS_W_F16 + BIAS_F32) {     // expanded biases (f32)
        int b = idx - WS_W_F16;
        float* bd = (float*)(ws + WS_W_F16);
        if (b < 768) {
            int type = b >> 8, r = b & 255;
            int c = r >> 6, n = (r >> 5) & 1, kg = (r >> 4) & 1, e = r & 15;
            int col = 64*c + 32*n + 4*kg + (e & 3) + 8*(e >> 2);
            bd[b] = (type == 0) ? gb[col] : (type == 1) ? gb[256 + col] : ob[col];
        } else {
            int i = b - 768;
            int n = (i >> 5) & 1, kg = (i >> 4) & 1, e = i & 15;
            bd[b] = pb[32*n + 4*kg + (e & 3) + 8*(e >> 2)];
        }
    }
}

__device__ __forceinline__ float sigm(float x)  { return 1.0f/(1.0f+__expf(-x)); }
__device__ __forceinline__ float tanh_(float x) { return 1.0f - 2.0f/(1.0f+__expf(2.0f*x)); }

// stage one 32KB panel (8 waves x 4 gll16). LDS dest linear; global source
// pre-applies the inverse chunk-XOR layout permutation.
__device__ __forceinline__ void stage(const uint8_t* __restrict__ Wp,
                                      u8l* slot, int w, int lane)
{
    #pragma unroll
    for (int i = 0; i < 4; ++i) {
        int d  = w*4096 + i*1024;
        int dl = d + lane*16;
        int chunk = (dl>>7)&31, sl = (dl>>4)&7;
        int row = ((dl>>12)<<3) | (sl ^ (chunk&7));
        int s   = row*512 + chunk*16;
        __builtin_amdgcn_global_load_lds(
            (const __attribute__((address_space(1))) uint32_t*)(Wp + s),
            (AS3 uint32_t*)(slot + d), 16, 0, 0);
    }
}

// load f32x16 bias (broadcast within kg-half)
__device__ __forceinline__ f32x16 ldbias(cu8l* p) {
    f32x16 r;
    #pragma unroll
    for (int j = 0; j < 4; ++j) {
        f32x4 t = *(const AS3 f32x4*)(p + j*16);
        r[j*4+0]=t[0]; r[j*4+1]=t[1]; r[j*4+2]=t[2]; r[j*4+3]=t[3];
    }
    return r;
}

// pack 4 f16x2 words (C-layout e-pattern, 8 outcols) -> B-frag f16x8.
// kg'=0: [self e0..3 | partner e0..3]; kg'=1: [partner e4..7 | self e4..7].
__device__ __forceinline__ f16x8 pk8(uint32_t w01, uint32_t w23,
                                     uint32_t w45, uint32_t w67, int kg) {
    uint32_t s01 = __shfl_xor(w01, 32, 64);
    uint32_t s23 = __shfl_xor(w23, 32, 64);
    uint32_t s45 = __shfl_xor(w45, 32, 64);
    uint32_t s67 = __shfl_xor(w67, 32, 64);
    u32x4 u = { kg ? s45 : w01, kg ? s67 : w23,
                kg ? w45 : s01, kg ? w67 : s23 };
    return __builtin_bit_cast(f16x8, u);
}
// sigmoid-activate 8 accumulator entries (off=0 or 8) and pack
__device__ __forceinline__ f16x8 pkS(const f32x16& a, int off, int kg) {
    f16x2 a01 = {(_Float16)sigm(a[off+0]), (_Float16)sigm(a[off+1])};
    f16x2 a23 = {(_Float16)sigm(a[off+2]), (_Float16)sigm(a[off+3])};
    f16x2 a45 = {(_Float16)sigm(a[off+4]), (_Float16)sigm(a[off+5])};
    f16x2 a67 = {(_Float16)sigm(a[off+6]), (_Float16)sigm(a[off+7])};
    return pk8(__builtin_bit_cast(uint32_t, a01), __builtin_bit_cast(uint32_t, a23),
               __builtin_bit_cast(uint32_t, a45), __builtin_bit_cast(uint32_t, a67), kg);
}
// tanh-activate and pack
__device__ __forceinline__ f16x8 pkT(const f32x16& a, int off, int kg) {
    f16x2 a01 = {(_Float16)tanh_(a[off+0]), (_Float16)tanh_(a[off+1])};
    f16x2 a23 = {(_Float16)tanh_(a[off+2]), (_Float16)tanh_(a[off+3])};
    f16x2 a45 = {(_Float16)tanh_(a[off+4]), (_Float16)tanh_(a[off+5])};
    f16x2 a67 = {(_Float16)tanh_(a[off+6]), (_Float16)tanh_(a[off+7])};
    return pk8(__builtin_bit_cast(uint32_t, a01), __builtin_bit_cast(uint32_t, a23),
               __builtin_bit_cast(uint32_t, a45), __builtin_bit_cast(uint32_t, a67), kg);
}

// one panel GEMM: acc_n += W[32n+(l&31), k] * B (B = reg-resident h or rh)
__device__ __forceinline__ void gemm2(cu8l* pan, int R0, int R1,
                                      const f16x8* B, f32x16& a0, f32x16& a1) {
    #pragma unroll
    for (int ks = 0; ks < 16; ++ks) {
        const int xk = ((2*ks)&7) << 4;
        f16x8 w0 = *(const AS3 f16x8*)(pan + ((R0 ^ xk) + ks*256));
        f16x8 w1 = *(const AS3 f16x8*)(pan + ((R1 ^ xk) + ks*256));
        a0 = __builtin_amdgcn_mfma_f32_32x32x16_f16(w0, B[ks], a0, 0, 0, 0);
        a1 = __builtin_amdgcn_mfma_f32_32x32x16_f16(w1, B[ks], a1, 0, 0, 0);
    }
}

// phase: wait panel (per-wave vmcnt(4): 2 stages of 4 in flight) -> barrier
// -> stage 2-ahead -> compute
#define PHASE(SP, ...) do {                                                 \
    asm volatile("s_waitcnt vmcnt(4)" ::: "memory");                        \
    asm volatile("s_waitcnt lgkmcnt(0)" ::: "memory");                      \
    __builtin_amdgcn_s_barrier();                                           \
    asm volatile("" ::: "memory");                                          \
    stage(W + (SP)*32768, WbL + sS*32768, w, lane);                         \
    { cu8l* pan = WbL + sC*32768; __VA_ARGS__; }                            \
    sC = (sC == 2) ? 0 : sC + 1;                                            \
    sS = (sS == 2) ? 0 : sS + 1;                                            \
} while (0)

__global__ __launch_bounds__(512, 1)
void gru_dec(const float* __restrict__ h_in, const _Float16* __restrict__ Wf,
             float* __restrict__ out)
{
    __shared__ __align__(16) uint8_t lds_[101632];
    u8l* ldsb = (u8l*)lds_;
    u8l* WbL  = ldsb;                     // 3 x 32KB panel ring
    u8l* biasL = ldsb + 98304;            // 3.3KB expanded biases
    const uint8_t* W = (const uint8_t*)Wf;

    const int tid  = threadIdx.x;
    const int lane = tid & 63;
    const int w    = tid >> 6;            // wave 0..7, owns 32 rows
    const int bl31 = lane & 31;
    const int kg   = lane >> 5;
    const int l7   = lane & 7;
    const size_t rowg = (size_t)blockIdx.x*256 + w*32 + bl31;

    // ---- h -> registers as B-frags: h[ks] = h[rowg, 16ks+8kg+0..7] ----
    f16x8 h[16], rh[16], hn[16];
    {
        const float* hs = h_in + rowg*256 + kg*8;
        #pragma unroll
        for (int ks = 0; ks < 16; ++ks) {
            f32x4 x = *(const f32x4*)(hs + ks*16);
            f32x4 y = *(const f32x4*)(hs + ks*16 + 4);
            f16x8 v = {(_Float16)x[0],(_Float16)x[1],(_Float16)x[2],(_Float16)x[3],
                       (_Float16)y[0],(_Float16)y[1],(_Float16)y[2],(_Float16)y[3]};
            h[ks] = v;
        }
    }
    // ---- biases ws -> LDS ----
    {
        const float* bsrc = (const float*)(Wf + WS_W_F16);
        for (int i = tid; i < BIAS_F32; i += 512)
            *(AS3 float*)(biasL + i*4) = bsrc[i];
    }
    __syncthreads();                      // drains h loads + bias writes

    // per-lane panel-read bases (chunk-XOR layout)
    const int R0 = ((bl31 >> 3))*4096 + kg*128 + ((l7 ^ kg) << 4);
    const int R1 = R0 + 4*4096;
    cu8l* bK = biasL + kg*64;

    stage(W + 0*32768, WbL,         w, lane);   // panel r0
    stage(W + 1*32768, WbL + 32768, w, lane);   // panel r1
    int sC = 0, sS = 2;

    for (int t = 0; t < TSTEPS; ++t) {
        f32x16 o0, o1;
        f16x8 zb[4];

        // ---- r gates (panels 0..3): rh[4c+i] = sigm(h@Wr_c + rb) * h ----
#define RPH(SP_STG, C)                                                        \
        PHASE(SP_STG, {                                                       \
            f32x16 a0 = ldbias(bK + (C)*256);                                 \
            f32x16 a1 = ldbias(bK + (C)*256 + 128);                           \
            gemm2(pan, R0, R1, h, a0, a1);                                    \
            rh[4*(C)+0] = pkS(a0, 0, kg)*h[4*(C)+0];                          \
            rh[4*(C)+1] = pkS(a0, 8, kg)*h[4*(C)+1];                          \
            rh[4*(C)+2] = pkS(a1, 0, kg)*h[4*(C)+2];                          \
            rh[4*(C)+3] = pkS(a1, 8, kg)*h[4*(C)+3]; })
        RPH(2, 0); RPH(3, 1); RPH(4, 2); RPH(8, 3);
#undef RPH

        // ---- per chunk c: z -> W1 -> W2+combine ----
#define ZPH(SP_STG, C)                                                        \
        PHASE(SP_STG, {                                                       \
            f32x16 a0 = ldbias(bK + 1024 + (C)*256);                          \
            f32x16 a1 = ldbias(bK + 1024 + (C)*256 + 128);                    \
            gemm2(pan, R0, R1, h, a0, a1);                                    \
            zb[0] = pkS(a0, 0, kg); zb[1] = pkS(a0, 8, kg);                   \
            zb[2] = pkS(a1, 0, kg); zb[3] = pkS(a1, 8, kg); })
#define W1PH(SP_STG, C)                                                       \
        PHASE(SP_STG, {                                                       \
            o0 = ldbias(bK + 2048 + (C)*256);                                 \
            o1 = ldbias(bK + 2048 + (C)*256 + 128);                           \
            gemm2(pan, R0, R1, h, o0, o1); })
#define W2PH(SP_STG, C)                                                       \
        PHASE(SP_STG, {                                                       \
            gemm2(pan, R0, R1, rh, o0, o1);                                   \
            f16x8 u0 = pkT(o0, 0, kg), u1 = pkT(o0, 8, kg);                   \
            f16x8 u2 = pkT(o1, 0, kg), u3 = pkT(o1, 8, kg);                   \
            hn[4*(C)+0] = u0 + zb[0]*(h[4*(C)+0] - u0);                       \
            hn[4*(C)+1] = u1 + zb[1]*(h[4*(C)+1] - u1);                       \
            hn[4*(C)+2] = u2 + zb[2]*(h[4*(C)+2] - u2);                       \
            hn[4*(C)+3] = u3 + zb[3]*(h[4*(C)+3] - u3); })

        ZPH(12, 0); W1PH(5, 0); W2PH(9,  0);
        ZPH(13, 1); W1PH(6, 1); W2PH(10, 1);
        ZPH(14, 2); W1PH(7, 2); W2PH(11, 2);
        ZPH(15, 3); W1PH(16,3); W2PH(0,  3);
#undef ZPH
#undef W1PH
#undef W2PH

        // h <- h_new
        #pragma unroll
        for (int i = 0; i < 16; ++i) h[i] = hn[i];

        // ---- proj (panel 16): out_t = h_new @ Wp^T + pb ----
        PHASE(1, {
            f32x16 a0 = ldbias(bK + 3072);
            f32x16 a1 = ldbias(bK + 3072 + 128);
            gemm2(pan, R0, R1, h, a0, a1);
            float* op = out + (rowg*TSTEPS + t)*64 + 4*kg;
            _Pragma("unroll")
            for (int j = 0; j < 4; ++j) {
                f32x4 v0 = {a0[4*j], a0[4*j+1], a0[4*j+2], a0[4*j+3]};
                f32x4 v1 = {a1[4*j], a1[4*j+1], a1[4*j+2], a1[4*j+3]};
                *(f32x4*)(op + 8*j)      = v0;
                *(f32x4*)(op + 32 + 8*j) = v1;
            }
        });
    }
}

extern "C" void kernel_launch(void* const* d_in, const int* in_sizes, int n_in,
                              void* d_out, int out_size, void* d_ws, size_t ws_size,
                              hipStream_t stream) {
    // inputs: 0:x(=12) 1:h 2:gate_w 3:gate_b 4:out_w 5:out_b 6:proj_w 7:proj_b
    const float* h  = (const float*)d_in[1];
    const float* gw = (const float*)d_in[2];
    const float* gb = (const float*)d_in[3];
    const float* ow = (const float*)d_in[4];
    const float* ob = (const float*)d_in[5];
    const float* pw = (const float*)d_in[6];
    const float* pb = (const float*)d_in[7];
    if (ws_size < (size_t)WS_BYTES) return;
    _Float16* ws = (_Float16*)d_ws;

    hipLaunchKernelGGL(prep_weights, dim3((WS_W_F16 + BIAS_F32 + 255)/256), dim3(256),
                       0, stream, gw, ow, pw, gb, ob, pb, ws);
    hipLaunchKernelGGL(gru_dec, dim3(65536/256), dim3(512), 0, stream,
                       h, ws, (float*)d_out);
}